// Round 10
// baseline (397.308 us; speedup 1.0000x reference)
//
#include <hip/hip_runtime.h>
#include <hip/hip_fp16.h>
#include <hip/hip_cooperative_groups.h>

namespace cg = cooperative_groups;

// GCN 2-layer. Pipeline (5 launches):
//   preproc (cooperative: hist->rowscan->topscan->scatter->bsort, grid.sync)
//   -> gemm1 -> agg1 -> gemm2 -> agg2
// R9 post-mortem: feature-chunking conserved gather instrs but lost to
// multi-pass overhead (272 vs 252) -- reverted. Preprocessing (5 kernels,
// ~100 us aggregate) fused into one cooperative kernel. Agg gathers widened
// to 8 B/lane (uint2): half the instructions of R8 at same byte volume.

#define BSHIFT 8
#define BNODES 256
#define NB 256       // partition blocks == grid of preproc
#define BSTRIDE 512  // blkcnt row stride

union H8 {  // 8 fp16 = 16 B (static-index use only! R6 lesson)
    uint4 u;
    __half2 h[4];
};
union H4 {  // 4 fp16 = 8 B (static-index use only)
    uint2 u;
    __half2 h[2];
};

// ---- fused preprocessing (cooperative) ----
// P1: per-block bucket hist -> blkcnt[b][bin]
// P2: per-bin exclusive scan across blocks (in place), bin totals
// P3: exclusive scan of bin totals -> base[]
// P4: scatter via LDS cursors -> packed (bucket-grouped, (src<<8)|dstLocal)
// P5: per-bucket LDS counting sort -> ssrc (node-grouped), off, dinv
__global__ __launch_bounds__(256) void preproc_kernel(
    const int* __restrict__ src, const int* __restrict__ dst,
    int* __restrict__ blkcnt, int* __restrict__ rowtot, int* __restrict__ base,
    int* __restrict__ packed, int* __restrict__ ssrc, int* __restrict__ off,
    float* __restrict__ dinv, int E, int N, int B) {
    cg::grid_group grid = cg::this_grid();
    __shared__ int h[512];
    __shared__ int cur[512];
    int t = threadIdx.x, b = blockIdx.x;
    int per = (E + NB - 1) / NB;
    int lo = b * per, hi = min(lo + per, E);

    // P1: histogram this block's edge slice
    for (int i = t; i < 512; i += 256) h[i] = 0;
    __syncthreads();
    for (int i = lo + t; i < hi; i += 256) atomicAdd(&h[dst[i] >> BSHIFT], 1);
    __syncthreads();
    for (int i = t; i < B; i += 256) blkcnt[b * BSTRIDE + i] = h[i];
    grid.sync();

    // P2: per-bin scan across NB block counts (bins b, b+256)
    for (int bin = b; bin < B; bin += NB) {
        int v = blkcnt[t * BSTRIDE + bin];
        cur[t] = v;
        __syncthreads();
#pragma unroll
        for (int d = 1; d < 256; d <<= 1) {
            int u = (t >= d) ? cur[t - d] : 0;
            __syncthreads();
            cur[t] += u;
            __syncthreads();
        }
        blkcnt[t * BSTRIDE + bin] = cur[t] - v;  // block-exclusive prefix
        if (t == 255) rowtot[bin] = cur[255];
        __syncthreads();
    }
    grid.sync();

    // P3: block 0 scans bin totals (two 256-wide passes covering 512)
    if (b == 0) {
        int a0 = (t < B) ? rowtot[t] : 0;
        int a1 = (t + 256 < B) ? rowtot[t + 256] : 0;
        cur[t] = a0;
        __syncthreads();
#pragma unroll
        for (int d = 1; d < 256; d <<= 1) {
            int u = (t >= d) ? cur[t - d] : 0;
            __syncthreads();
            cur[t] += u;
            __syncthreads();
        }
        int pA = cur[t] - a0;
        int TA = cur[255];
        __syncthreads();
        cur[t] = a1;
        __syncthreads();
#pragma unroll
        for (int d = 1; d < 256; d <<= 1) {
            int u = (t >= d) ? cur[t - d] : 0;
            __syncthreads();
            cur[t] += u;
            __syncthreads();
        }
        int pB = cur[t] - a1;
        if (t < B) base[t] = pA;
        if (t + 256 < B) base[t + 256] = TA + pB;
        if (t == 0) {
            base[B] = E;
            off[N] = E;
        }
    }
    grid.sync();

    // P4: scatter this block's slice via LDS cursors (no global atomics)
    for (int i = t; i < B; i += 256) cur[i] = base[i] + blkcnt[b * BSTRIDE + i];
    __syncthreads();
    for (int i = lo + t; i < hi; i += 256) {
        int d = dst[i];
        int pos = atomicAdd(&cur[d >> BSHIFT], 1);
        packed[pos] = (src[i] << BSHIFT) | (d & (BNODES - 1));
    }
    grid.sync();

    // P5: per-bucket counting sort (buckets b, b+256)
    for (int bk = b; bk < B; bk += NB) {
        h[t] = 0;
        __syncthreads();
        int l2 = base[bk], h2 = base[bk + 1];
        for (int i = l2 + t; i < h2; i += 256)
            atomicAdd(&h[packed[i] & (BNODES - 1)], 1);
        __syncthreads();
        int deg = h[t];
        __syncthreads();
        h[t] = deg;
        __syncthreads();
#pragma unroll
        for (int d = 1; d < 256; d <<= 1) {
            int u = (t >= d) ? h[t - d] : 0;
            __syncthreads();
            h[t] += u;
            __syncthreads();
        }
        int excl = h[t] - deg;
        cur[t] = excl;
        int node = (bk << BSHIFT) + t;
        if (node < N) {
            off[node] = l2 + excl;
            dinv[node] = rsqrtf((float)(deg + 1));
        }
        __syncthreads();
        for (int i = l2 + t; i < h2; i += 256) {
            int p = packed[i];
            int pos = atomicAdd(&cur[p & (BNODES - 1)], 1);
            ssrc[l2 + pos] = p >> BSHIFT;
        }
        __syncthreads();
    }
}

// hsh = fp16((x@W1)*dinv). 2 rows/thread, W1 broadcast from LDS.
__global__ __launch_bounds__(256) void gemm1_kernel(
    const float* __restrict__ x, const float* __restrict__ W1,
    const float* __restrict__ dinv, __half* __restrict__ hsh, int N) {
    __shared__ float4 Ws[64 * 16];
    int t = threadIdx.x;
    const float4* W4 = (const float4*)W1;
    for (int i = t; i < 1024; i += 256) Ws[i] = W4[i];
    __syncthreads();
    int ra = blockIdx.x * 512 + t;
    int rb = ra + 256;
    if (ra >= N) return;
    bool hb = rb < N;
    const float4* xa = (const float4*)(x + (size_t)ra * 64);
    const float4* xb = (const float4*)(x + (size_t)rb * 64);
    float4 acc0[16], acc1[16];
#pragma unroll
    for (int j = 0; j < 16; j++) {
        acc0[j] = make_float4(0.f, 0.f, 0.f, 0.f);
        acc1[j] = make_float4(0.f, 0.f, 0.f, 0.f);
    }
    for (int k4 = 0; k4 < 16; k4++) {
        float4 x0 = xa[k4];
        float4 x1 = hb ? xb[k4] : make_float4(0.f, 0.f, 0.f, 0.f);
#pragma unroll
        for (int kk = 0; kk < 4; kk++) {
            float a0 = ((const float*)&x0)[kk];
            float a1 = ((const float*)&x1)[kk];
            const float4* wr = &Ws[(k4 * 4 + kk) * 16];
#pragma unroll
            for (int j = 0; j < 16; j++) {
                float4 w = wr[j];
                acc0[j].x += a0 * w.x; acc0[j].y += a0 * w.y;
                acc0[j].z += a0 * w.z; acc0[j].w += a0 * w.w;
                acc1[j].x += a1 * w.x; acc1[j].y += a1 * w.y;
                acc1[j].z += a1 * w.z; acc1[j].w += a1 * w.w;
            }
        }
    }
    float d0 = dinv[ra];
    uint4* ha = (uint4*)(hsh + (size_t)ra * 64);
#pragma unroll
    for (int j = 0; j < 8; j++) {
        H8 p;
        float4 v0 = acc0[2 * j], v1 = acc0[2 * j + 1];
        p.h[0] = __floats2half2_rn(v0.x * d0, v0.y * d0);
        p.h[1] = __floats2half2_rn(v0.z * d0, v0.w * d0);
        p.h[2] = __floats2half2_rn(v1.x * d0, v1.y * d0);
        p.h[3] = __floats2half2_rn(v1.z * d0, v1.w * d0);
        ha[j] = p.u;
    }
    if (hb) {
        float d1 = dinv[rb];
        uint4* hbp = (uint4*)(hsh + (size_t)rb * 64);
#pragma unroll
        for (int j = 0; j < 8; j++) {
            H8 p;
            float4 v0 = acc1[2 * j], v1 = acc1[2 * j + 1];
            p.h[0] = __floats2half2_rn(v0.x * d1, v0.y * d1);
            p.h[1] = __floats2half2_rn(v0.z * d1, v0.w * d1);
            p.h[2] = __floats2half2_rn(v1.x * d1, v1.y * d1);
            p.h[3] = __floats2half2_rn(v1.z * d1, v1.w * d1);
            hbp[j] = p.u;
        }
    }
}

// Layer-1 aggregate: 4 nodes/wave, 16 lanes/node, 8 B/lane (4 fp16).
__global__ __launch_bounds__(256) void agg1_kernel(
    const uint2* __restrict__ hs4, const int* __restrict__ ssrc,
    const int* __restrict__ off, const float* __restrict__ dinv,
    const float* __restrict__ b1, uint2* __restrict__ h14, int N) {
    int lane = threadIdx.x & 63;
    int wid = (blockIdx.x * 256 + threadIdx.x) >> 6;
    int node = wid * 4 + (lane >> 4);
    int fq = lane & 15;  // feats 4*fq .. 4*fq+3
    if (node >= N) return;
    H4 s;
    s.u = hs4[(size_t)node * 16 + fq];  // self-loop
    float2 aA0 = __half22float2(s.h[0]);
    float2 aA1 = __half22float2(s.h[1]);
    float2 aB0 = make_float2(0.f, 0.f), aB1 = make_float2(0.f, 0.f);
    int lo = off[node], hi = off[node + 1];
    int e = lo;
    for (; e + 4 <= hi; e += 4) {
        int i0 = ssrc[e], i1 = ssrc[e + 1], i2 = ssrc[e + 2], i3 = ssrc[e + 3];
        H4 v0, v1, v2, v3;
        v0.u = hs4[(size_t)i0 * 16 + fq];
        v1.u = hs4[(size_t)i1 * 16 + fq];
        v2.u = hs4[(size_t)i2 * 16 + fq];
        v3.u = hs4[(size_t)i3 * 16 + fq];
        float2 f;
        f = __half22float2(v0.h[0]); aA0.x += f.x; aA0.y += f.y;
        f = __half22float2(v0.h[1]); aA1.x += f.x; aA1.y += f.y;
        f = __half22float2(v1.h[0]); aB0.x += f.x; aB0.y += f.y;
        f = __half22float2(v1.h[1]); aB1.x += f.x; aB1.y += f.y;
        f = __half22float2(v2.h[0]); aA0.x += f.x; aA0.y += f.y;
        f = __half22float2(v2.h[1]); aA1.x += f.x; aA1.y += f.y;
        f = __half22float2(v3.h[0]); aB0.x += f.x; aB0.y += f.y;
        f = __half22float2(v3.h[1]); aB1.x += f.x; aB1.y += f.y;
    }
    for (; e < hi; e++) {
        H4 v;
        v.u = hs4[(size_t)ssrc[e] * 16 + fq];
        float2 f = __half22float2(v.h[0]);
        aA0.x += f.x; aA0.y += f.y;
        f = __half22float2(v.h[1]);
        aA1.x += f.x; aA1.y += f.y;
    }
    float di = dinv[node];
    float4 bb = ((const float4*)b1)[fq];
    float r0 = fmaxf((aA0.x + aB0.x) * di + bb.x, 0.f);
    float r1 = fmaxf((aA0.y + aB0.y) * di + bb.y, 0.f);
    float r2 = fmaxf((aA1.x + aB1.x) * di + bb.z, 0.f);
    float r3 = fmaxf((aA1.y + aB1.y) * di + bb.w, 0.f);
    H4 o;
    o.h[0] = __floats2half2_rn(r0, r1);
    o.h[1] = __floats2half2_rn(r2, r3);
    h14[(size_t)node * 16 + fq] = o.u;
}

// gsh = fp16((h1@W2)*dinv). One row/thread; direct __half2 loads (R6 lesson).
__global__ __launch_bounds__(256) void gemm2_kernel(
    const __half* __restrict__ h1h, const float* __restrict__ W2,
    const float* __restrict__ dinv, __half* __restrict__ gsh, int N) {
    __shared__ float4 Ws[64 * 8];
    int t = threadIdx.x;
    const float4* W4 = (const float4*)W2;
    for (int i = t; i < 512; i += 256) Ws[i] = W4[i];
    __syncthreads();
    int r = blockIdx.x * 256 + t;
    if (r >= N) return;
    const __half2* xr = (const __half2*)(h1h + (size_t)r * 64);
    float4 acc[8];
#pragma unroll
    for (int j = 0; j < 8; j++) acc[j] = make_float4(0.f, 0.f, 0.f, 0.f);
#pragma unroll
    for (int k2 = 0; k2 < 32; k2++) {
        float2 f = __half22float2(xr[k2]);
        const float4* w0 = &Ws[(2 * k2) * 8];
        const float4* w1 = &Ws[(2 * k2 + 1) * 8];
#pragma unroll
        for (int j = 0; j < 8; j++) {
            float4 wa = w0[j];
            acc[j].x += f.x * wa.x; acc[j].y += f.x * wa.y;
            acc[j].z += f.x * wa.z; acc[j].w += f.x * wa.w;
        }
#pragma unroll
        for (int j = 0; j < 8; j++) {
            float4 wb = w1[j];
            acc[j].x += f.y * wb.x; acc[j].y += f.y * wb.y;
            acc[j].z += f.y * wb.z; acc[j].w += f.y * wb.w;
        }
    }
    float d0 = dinv[r];
    uint4* g = (uint4*)(gsh + (size_t)r * 32);
#pragma unroll
    for (int j = 0; j < 4; j++) {
        H8 p;
        float4 v0 = acc[2 * j], v1 = acc[2 * j + 1];
        p.h[0] = __floats2half2_rn(v0.x * d0, v0.y * d0);
        p.h[1] = __floats2half2_rn(v0.z * d0, v0.w * d0);
        p.h[2] = __floats2half2_rn(v1.x * d0, v1.y * d0);
        p.h[3] = __floats2half2_rn(v1.z * d0, v1.w * d0);
        g[j] = p.u;
    }
}

// Layer-2 aggregate: 8 nodes/wave, 8 lanes/node, 8 B/lane. fp32 float4 out.
__global__ __launch_bounds__(256) void agg2_kernel(
    const uint2* __restrict__ gs4, const int* __restrict__ ssrc,
    const int* __restrict__ off, const float* __restrict__ dinv,
    const float* __restrict__ b2, float* __restrict__ out, int N) {
    int lane = threadIdx.x & 63;
    int wid = (blockIdx.x * 256 + threadIdx.x) >> 6;
    int node = wid * 8 + (lane >> 3);
    int fq = lane & 7;  // feats 4*fq .. 4*fq+3
    if (node >= N) return;
    H4 s;
    s.u = gs4[(size_t)node * 8 + fq];  // self-loop
    float2 aA0 = __half22float2(s.h[0]);
    float2 aA1 = __half22float2(s.h[1]);
    float2 aB0 = make_float2(0.f, 0.f), aB1 = make_float2(0.f, 0.f);
    int lo = off[node], hi = off[node + 1];
    int e = lo;
    for (; e + 4 <= hi; e += 4) {
        int i0 = ssrc[e], i1 = ssrc[e + 1], i2 = ssrc[e + 2], i3 = ssrc[e + 3];
        H4 v0, v1, v2, v3;
        v0.u = gs4[(size_t)i0 * 8 + fq];
        v1.u = gs4[(size_t)i1 * 8 + fq];
        v2.u = gs4[(size_t)i2 * 8 + fq];
        v3.u = gs4[(size_t)i3 * 8 + fq];
        float2 f;
        f = __half22float2(v0.h[0]); aA0.x += f.x; aA0.y += f.y;
        f = __half22float2(v0.h[1]); aA1.x += f.x; aA1.y += f.y;
        f = __half22float2(v1.h[0]); aB0.x += f.x; aB0.y += f.y;
        f = __half22float2(v1.h[1]); aB1.x += f.x; aB1.y += f.y;
        f = __half22float2(v2.h[0]); aA0.x += f.x; aA0.y += f.y;
        f = __half22float2(v2.h[1]); aA1.x += f.x; aA1.y += f.y;
        f = __half22float2(v3.h[0]); aB0.x += f.x; aB0.y += f.y;
        f = __half22float2(v3.h[1]); aB1.x += f.x; aB1.y += f.y;
    }
    for (; e < hi; e++) {
        H4 v;
        v.u = gs4[(size_t)ssrc[e] * 8 + fq];
        float2 f = __half22float2(v.h[0]);
        aA0.x += f.x; aA0.y += f.y;
        f = __half22float2(v.h[1]);
        aA1.x += f.x; aA1.y += f.y;
    }
    float di = dinv[node];
    float4 bb = ((const float4*)b2)[fq];
    float4 r;
    r.x = (aA0.x + aB0.x) * di + bb.x;
    r.y = (aA0.y + aB0.y) * di + bb.y;
    r.z = (aA1.x + aB1.x) * di + bb.z;
    r.w = (aA1.y + aB1.y) * di + bb.w;
    ((float4*)out)[(size_t)node * 8 + fq] = r;
}

extern "C" void kernel_launch(void* const* d_in, const int* in_sizes, int n_in,
                              void* d_out, int out_size, void* d_ws,
                              size_t ws_size, hipStream_t stream) {
    const float* x  = (const float*)d_in[0];
    const int* ei   = (const int*)d_in[1];
    const float* W1 = (const float*)d_in[2];
    const float* b1 = (const float*)d_in[3];
    const float* W2 = (const float*)d_in[4];
    const float* b2 = (const float*)d_in[5];
    int N = in_sizes[0] / 64;
    int E = in_sizes[1] / 2;
    const int* src = ei;
    const int* dst = ei + E;
    int B = (N + BNODES - 1) >> BSHIFT;  // 391 for N=100000

    char* ws = (char*)d_ws;
    size_t o = 0;
    auto align16 = [&o]() { o = (o + 15) & ~(size_t)15; };
    int* blkcnt  = (int*)(ws + o); o += (size_t)NB * BSTRIDE * 4; align16();
    int* rowtot  = (int*)(ws + o); o += 512 * 4; align16();
    int* base    = (int*)(ws + o); o += 513 * 4; align16();
    int* off     = (int*)(ws + o); o += ((size_t)N + 1) * 4; align16();
    float* dinv  = (float*)(ws + o); o += (size_t)N * 4; align16();
    int* packed  = (int*)(ws + o); o += (size_t)E * 4; align16();
    int* ssrc    = (int*)(ws + o); o += (size_t)E * 4; align16();
    __half* hsh  = (__half*)(ws + o); o += (size_t)N * 64 * 2; align16();
    __half* h1h  = (__half*)(ws + o); o += (size_t)N * 64 * 2; align16();
    __half* gsh  = hsh;  // hsh dead after agg1; reuse (N*32 fp16)
    float* outp  = (float*)d_out;

    void* kargs[] = {(void*)&src,    (void*)&dst,  (void*)&blkcnt,
                     (void*)&rowtot, (void*)&base, (void*)&packed,
                     (void*)&ssrc,   (void*)&off,  (void*)&dinv,
                     (void*)&E,      (void*)&N,    (void*)&B};
    hipLaunchCooperativeKernel((void*)preproc_kernel, dim3(NB), dim3(256),
                               kargs, 0, stream);
    gemm1_kernel<<<(N + 511) / 512, 256, 0, stream>>>(x, W1, dinv, hsh, N);
    int g1 = (int)(((size_t)((N + 3) / 4) * 64 + 255) / 256);
    agg1_kernel<<<g1, 256, 0, stream>>>((const uint2*)hsh, ssrc, off, dinv, b1,
                                        (uint2*)h1h, N);
    gemm2_kernel<<<(N + 255) / 256, 256, 0, stream>>>(h1h, W2, dinv, gsh, N);
    int g2 = (int)(((size_t)((N + 7) / 8) * 64 + 255) / 256);
    agg2_kernel<<<g2, 256, 0, stream>>>((const uint2*)gsh, ssrc, off, dinv, b2,
                                        outp, N);
}

// Round 11
// 287.682 us; speedup vs baseline: 1.3811x; 1.3811x over previous
//
#include <hip/hip_runtime.h>
#include <hip/hip_fp16.h>

// GCN 2-layer. Pipeline (7 launches):
//   blkhist -> rowscan(+fused topscan via last-block) -> scatter2 -> bsort
//   -> gemm1 -> agg1+gemm2 (fused) -> agg2
// R10 post-mortem: cooperative mega-fusion pinned all phases at 256 blocks /
// grid.sync cost -> 177 us doing ~30 us of work. Reverted to split kernels;
// launch count cut instead by last-block fusion (topscan) and epilogue
// fusion (gemm2 into agg1). Aggs keep R10's 8 B/lane uint2 gathers.

#define BSHIFT 8
#define BNODES 256
#define NB 256       // partition blocks
#define BSTRIDE 512  // blkcnt row stride

union H8 {  // 8 fp16 = 16 B (static-index use only! R6 lesson)
    uint4 u;
    __half2 h[4];
};
union H4 {  // 4 fp16 = 8 B (static-index use only)
    uint2 u;
    __half2 h[2];
};

// Per-block bucket histogram: blkcnt[blk*BSTRIDE + bin]. Also zeroes done.
__global__ __launch_bounds__(256) void blkhist_kernel(
    const int* __restrict__ dst, int E, int* __restrict__ blkcnt,
    int* __restrict__ done, int B) {
    __shared__ int h[512];
    int t = threadIdx.x, b = blockIdx.x;
    if (b == 0 && t == 0) *done = 0;
    for (int i = t; i < 512; i += 256) h[i] = 0;
    __syncthreads();
    int per = (E + NB - 1) / NB;
    int lo = b * per;
    int hi = min(lo + per, E);
    for (int i = lo + t; i < hi; i += 256) atomicAdd(&h[dst[i] >> BSHIFT], 1);
    __syncthreads();
    for (int i = t; i < B; i += 256) blkcnt[b * BSTRIDE + i] = h[i];
}

// One block per bin: exclusive scan across NB block counts (in place), emit
// bin total. The LAST block to finish also scans bin totals -> base[].
__global__ __launch_bounds__(256) void rowscan_kernel(
    int* __restrict__ blkcnt, int* __restrict__ rowtot, int* __restrict__ base,
    int* __restrict__ off, int* __restrict__ done, int B, int E, int N) {
    __shared__ int s[256];
    __shared__ int isLast;
    int t = threadIdx.x, bin = blockIdx.x;
    int v = blkcnt[t * BSTRIDE + bin];
    s[t] = v;
    __syncthreads();
#pragma unroll
    for (int d = 1; d < 256; d <<= 1) {
        int u = (t >= d) ? s[t - d] : 0;
        __syncthreads();
        s[t] += u;
        __syncthreads();
    }
    blkcnt[t * BSTRIDE + bin] = s[t] - v;  // block-exclusive prefix
    if (t == 255) rowtot[bin] = s[255];
    __threadfence();  // release rowtot before signaling
    if (t == 0) isLast = (atomicAdd(done, 1) == gridDim.x - 1);
    __syncthreads();
    if (!isLast) return;
    __threadfence();  // acquire other blocks' rowtot
    // two-pass 256-wide exclusive scan over rowtot[0..B-1] (B <= 512)
    int a0 = (t < B) ? rowtot[t] : 0;
    int a1 = (t + 256 < B) ? rowtot[t + 256] : 0;
    __syncthreads();
    s[t] = a0;
    __syncthreads();
#pragma unroll
    for (int d = 1; d < 256; d <<= 1) {
        int u = (t >= d) ? s[t - d] : 0;
        __syncthreads();
        s[t] += u;
        __syncthreads();
    }
    int pA = s[t] - a0;
    int TA = s[255];
    __syncthreads();
    s[t] = a1;
    __syncthreads();
#pragma unroll
    for (int d = 1; d < 256; d <<= 1) {
        int u = (t >= d) ? s[t - d] : 0;
        __syncthreads();
        s[t] += u;
        __syncthreads();
    }
    int pB = s[t] - a1;
    if (t < B) base[t] = pA;
    if (t + 256 < B) base[t + 256] = TA + pB;
    if (t == 0) {
        base[B] = E;
        off[N] = E;
    }
}

// Scatter via LDS cursors seeded from precomputed bases. No global atomics.
__global__ __launch_bounds__(256) void scatter2_kernel(
    const int* __restrict__ src, const int* __restrict__ dst,
    const int* __restrict__ blkcnt, const int* __restrict__ base,
    int* __restrict__ packed, int E, int B) {
    __shared__ int cur[512];
    int t = threadIdx.x, b = blockIdx.x;
    for (int i = t; i < B; i += 256) cur[i] = base[i] + blkcnt[b * BSTRIDE + i];
    __syncthreads();
    int per = (E + NB - 1) / NB;
    int lo = b * per;
    int hi = min(lo + per, E);
    for (int i = lo + t; i < hi; i += 256) {
        int d = dst[i];
        int pos = atomicAdd(&cur[d >> BSHIFT], 1);
        packed[pos] = (src[i] << BSHIFT) | (d & (BNODES - 1));
    }
}

// Per-bucket LDS counting sort -> ssrc grouped by node; also off & dinv.
__global__ __launch_bounds__(256) void bsort_kernel(
    const int* __restrict__ packed, const int* __restrict__ base,
    int* __restrict__ ssrc, int* __restrict__ off, float* __restrict__ dinv,
    int N) {
    __shared__ int s[BNODES];
    __shared__ int cur[BNODES];
    int t = threadIdx.x, b = blockIdx.x;
    s[t] = 0;
    __syncthreads();
    int lo = base[b], hi = base[b + 1];
    for (int i = lo + t; i < hi; i += 256)
        atomicAdd(&s[packed[i] & (BNODES - 1)], 1);
    __syncthreads();
    int deg = s[t];
    __syncthreads();
    s[t] = deg;
    __syncthreads();
#pragma unroll
    for (int d = 1; d < BNODES; d <<= 1) {
        int v = (t >= d) ? s[t - d] : 0;
        __syncthreads();
        s[t] += v;
        __syncthreads();
    }
    int excl = s[t] - deg;
    cur[t] = excl;
    int node = (b << BSHIFT) + t;
    if (node < N) {
        off[node] = lo + excl;
        dinv[node] = rsqrtf((float)(deg + 1));
    }
    __syncthreads();
    for (int i = lo + t; i < hi; i += 256) {
        int p = packed[i];
        int pos = atomicAdd(&cur[p & (BNODES - 1)], 1);
        ssrc[lo + pos] = p >> BSHIFT;
    }
}

// hsh = fp16((x@W1)*dinv). 2 rows/thread, W1 broadcast from LDS.
__global__ __launch_bounds__(256) void gemm1_kernel(
    const float* __restrict__ x, const float* __restrict__ W1,
    const float* __restrict__ dinv, __half* __restrict__ hsh, int N) {
    __shared__ float4 Ws[64 * 16];
    int t = threadIdx.x;
    const float4* W4 = (const float4*)W1;
    for (int i = t; i < 1024; i += 256) Ws[i] = W4[i];
    __syncthreads();
    int ra = blockIdx.x * 512 + t;
    int rb = ra + 256;
    if (ra >= N) return;
    bool hb = rb < N;
    const float4* xa = (const float4*)(x + (size_t)ra * 64);
    const float4* xb = (const float4*)(x + (size_t)rb * 64);
    float4 acc0[16], acc1[16];
#pragma unroll
    for (int j = 0; j < 16; j++) {
        acc0[j] = make_float4(0.f, 0.f, 0.f, 0.f);
        acc1[j] = make_float4(0.f, 0.f, 0.f, 0.f);
    }
    for (int k4 = 0; k4 < 16; k4++) {
        float4 x0 = xa[k4];
        float4 x1 = hb ? xb[k4] : make_float4(0.f, 0.f, 0.f, 0.f);
#pragma unroll
        for (int kk = 0; kk < 4; kk++) {
            float a0 = ((const float*)&x0)[kk];
            float a1 = ((const float*)&x1)[kk];
            const float4* wr = &Ws[(k4 * 4 + kk) * 16];
#pragma unroll
            for (int j = 0; j < 16; j++) {
                float4 w = wr[j];
                acc0[j].x += a0 * w.x; acc0[j].y += a0 * w.y;
                acc0[j].z += a0 * w.z; acc0[j].w += a0 * w.w;
                acc1[j].x += a1 * w.x; acc1[j].y += a1 * w.y;
                acc1[j].z += a1 * w.z; acc1[j].w += a1 * w.w;
            }
        }
    }
    float d0 = dinv[ra];
    uint4* ha = (uint4*)(hsh + (size_t)ra * 64);
#pragma unroll
    for (int j = 0; j < 8; j++) {
        H8 p;
        float4 v0 = acc0[2 * j], v1 = acc0[2 * j + 1];
        p.h[0] = __floats2half2_rn(v0.x * d0, v0.y * d0);
        p.h[1] = __floats2half2_rn(v0.z * d0, v0.w * d0);
        p.h[2] = __floats2half2_rn(v1.x * d0, v1.y * d0);
        p.h[3] = __floats2half2_rn(v1.z * d0, v1.w * d0);
        ha[j] = p.u;
    }
    if (hb) {
        float d1 = dinv[rb];
        uint4* hbp = (uint4*)(hsh + (size_t)rb * 64);
#pragma unroll
        for (int j = 0; j < 8; j++) {
            H8 p;
            float4 v0 = acc1[2 * j], v1 = acc1[2 * j + 1];
            p.h[0] = __floats2half2_rn(v0.x * d1, v0.y * d1);
            p.h[1] = __floats2half2_rn(v0.z * d1, v0.w * d1);
            p.h[2] = __floats2half2_rn(v1.x * d1, v1.y * d1);
            p.h[3] = __floats2half2_rn(v1.z * d1, v1.w * d1);
            hbp[j] = p.u;
        }
    }
}

// Fused layer-1 aggregate + gemm2. Block = 16 nodes (4 waves x 4 nodes).
// Phase A: gather (4 nodes/wave, 16 lanes/node, 8 B/lane uint2), h1 -> LDS
// (fp32, never fp16-rounded). Phase B: gs = fp16((h1 @ W2) * dinv) from LDS.
__global__ __launch_bounds__(256) void agg1g2_kernel(
    const uint2* __restrict__ hs4, const int* __restrict__ ssrc,
    const int* __restrict__ off, const float* __restrict__ dinv,
    const float* __restrict__ b1, const float* __restrict__ W2,
    __half* __restrict__ gsh, int N) {
    __shared__ float W2s[64 * 32];  // 8 KB
    __shared__ float h1s[16 * 64];  // 4 KB
    int t = threadIdx.x;
    const float4* W4 = (const float4*)W2;
    for (int i = t; i < 512; i += 256) ((float4*)W2s)[i] = W4[i];
    int lane = t & 63;
    int node0 = blockIdx.x * 16;
    int node = node0 + (t >> 4);  // = node0 + wave*4 + (lane>>4)
    int fq = lane & 15;           // feats 4*fq .. 4*fq+3
    if (node < N) {
        H4 s;
        s.u = hs4[(size_t)node * 16 + fq];  // self-loop
        float2 aA0 = __half22float2(s.h[0]);
        float2 aA1 = __half22float2(s.h[1]);
        float2 aB0 = make_float2(0.f, 0.f), aB1 = make_float2(0.f, 0.f);
        int lo = off[node], hi = off[node + 1];
        int e = lo;
        for (; e + 4 <= hi; e += 4) {
            int i0 = ssrc[e], i1 = ssrc[e + 1], i2 = ssrc[e + 2],
                i3 = ssrc[e + 3];
            H4 v0, v1, v2, v3;
            v0.u = hs4[(size_t)i0 * 16 + fq];
            v1.u = hs4[(size_t)i1 * 16 + fq];
            v2.u = hs4[(size_t)i2 * 16 + fq];
            v3.u = hs4[(size_t)i3 * 16 + fq];
            float2 f;
            f = __half22float2(v0.h[0]); aA0.x += f.x; aA0.y += f.y;
            f = __half22float2(v0.h[1]); aA1.x += f.x; aA1.y += f.y;
            f = __half22float2(v1.h[0]); aB0.x += f.x; aB0.y += f.y;
            f = __half22float2(v1.h[1]); aB1.x += f.x; aB1.y += f.y;
            f = __half22float2(v2.h[0]); aA0.x += f.x; aA0.y += f.y;
            f = __half22float2(v2.h[1]); aA1.x += f.x; aA1.y += f.y;
            f = __half22float2(v3.h[0]); aB0.x += f.x; aB0.y += f.y;
            f = __half22float2(v3.h[1]); aB1.x += f.x; aB1.y += f.y;
        }
        for (; e < hi; e++) {
            H4 v;
            v.u = hs4[(size_t)ssrc[e] * 16 + fq];
            float2 f = __half22float2(v.h[0]);
            aA0.x += f.x; aA0.y += f.y;
            f = __half22float2(v.h[1]);
            aA1.x += f.x; aA1.y += f.y;
        }
        float di = dinv[node];
        float4 bb = ((const float4*)b1)[fq];
        float4 r;
        r.x = fmaxf((aA0.x + aB0.x) * di + bb.x, 0.f);
        r.y = fmaxf((aA0.y + aB0.y) * di + bb.y, 0.f);
        r.z = fmaxf((aA1.x + aB1.x) * di + bb.z, 0.f);
        r.w = fmaxf((aA1.y + aB1.y) * di + bb.w, 0.f);
        *(float4*)&h1s[(t >> 4) * 64 + 4 * fq] = r;
    }
    __syncthreads();
    // Phase B: gs[node][j], j = (t&15) and (t&15)+16 (bank-friendly split)
    int n = t >> 4;
    int gnode = node0 + n;
    if (gnode >= N) return;
    int j = t & 15;
    float a0 = 0.f, a1 = 0.f;
    const float* hrow = &h1s[n * 64];
#pragma unroll
    for (int k = 0; k < 64; k++) {
        float h = hrow[k];  // broadcast across the 16 lanes of node n
        a0 += h * W2s[k * 32 + j];
        a1 += h * W2s[k * 32 + j + 16];
    }
    float di = dinv[gnode];
    gsh[(size_t)gnode * 32 + j] = __float2half_rn(a0 * di);
    gsh[(size_t)gnode * 32 + j + 16] = __float2half_rn(a1 * di);
}

// Layer-2 aggregate: 8 nodes/wave, 8 lanes/node, 8 B/lane. fp32 float4 out.
__global__ __launch_bounds__(256) void agg2_kernel(
    const uint2* __restrict__ gs4, const int* __restrict__ ssrc,
    const int* __restrict__ off, const float* __restrict__ dinv,
    const float* __restrict__ b2, float* __restrict__ out, int N) {
    int lane = threadIdx.x & 63;
    int wid = (blockIdx.x * 256 + threadIdx.x) >> 6;
    int node = wid * 8 + (lane >> 3);
    int fq = lane & 7;  // feats 4*fq .. 4*fq+3
    if (node >= N) return;
    H4 s;
    s.u = gs4[(size_t)node * 8 + fq];  // self-loop
    float2 aA0 = __half22float2(s.h[0]);
    float2 aA1 = __half22float2(s.h[1]);
    float2 aB0 = make_float2(0.f, 0.f), aB1 = make_float2(0.f, 0.f);
    int lo = off[node], hi = off[node + 1];
    int e = lo;
    for (; e + 4 <= hi; e += 4) {
        int i0 = ssrc[e], i1 = ssrc[e + 1], i2 = ssrc[e + 2], i3 = ssrc[e + 3];
        H4 v0, v1, v2, v3;
        v0.u = gs4[(size_t)i0 * 8 + fq];
        v1.u = gs4[(size_t)i1 * 8 + fq];
        v2.u = gs4[(size_t)i2 * 8 + fq];
        v3.u = gs4[(size_t)i3 * 8 + fq];
        float2 f;
        f = __half22float2(v0.h[0]); aA0.x += f.x; aA0.y += f.y;
        f = __half22float2(v0.h[1]); aA1.x += f.x; aA1.y += f.y;
        f = __half22float2(v1.h[0]); aB0.x += f.x; aB0.y += f.y;
        f = __half22float2(v1.h[1]); aB1.x += f.x; aB1.y += f.y;
        f = __half22float2(v2.h[0]); aA0.x += f.x; aA0.y += f.y;
        f = __half22float2(v2.h[1]); aA1.x += f.x; aA1.y += f.y;
        f = __half22float2(v3.h[0]); aB0.x += f.x; aB0.y += f.y;
        f = __half22float2(v3.h[1]); aB1.x += f.x; aB1.y += f.y;
    }
    for (; e < hi; e++) {
        H4 v;
        v.u = gs4[(size_t)ssrc[e] * 8 + fq];
        float2 f = __half22float2(v.h[0]);
        aA0.x += f.x; aA0.y += f.y;
        f = __half22float2(v.h[1]);
        aA1.x += f.x; aA1.y += f.y;
    }
    float di = dinv[node];
    float4 bb = ((const float4*)b2)[fq];
    float4 r;
    r.x = (aA0.x + aB0.x) * di + bb.x;
    r.y = (aA0.y + aB0.y) * di + bb.y;
    r.z = (aA1.x + aB1.x) * di + bb.z;
    r.w = (aA1.y + aB1.y) * di + bb.w;
    ((float4*)out)[(size_t)node * 8 + fq] = r;
}

extern "C" void kernel_launch(void* const* d_in, const int* in_sizes, int n_in,
                              void* d_out, int out_size, void* d_ws,
                              size_t ws_size, hipStream_t stream) {
    const float* x  = (const float*)d_in[0];
    const int* ei   = (const int*)d_in[1];
    const float* W1 = (const float*)d_in[2];
    const float* b1 = (const float*)d_in[3];
    const float* W2 = (const float*)d_in[4];
    const float* b2 = (const float*)d_in[5];
    int N = in_sizes[0] / 64;
    int E = in_sizes[1] / 2;
    const int* src = ei;
    const int* dst = ei + E;
    int B = (N + BNODES - 1) >> BSHIFT;  // 391 for N=100000

    char* ws = (char*)d_ws;
    size_t o = 0;
    auto align16 = [&o]() { o = (o + 15) & ~(size_t)15; };
    int* blkcnt  = (int*)(ws + o); o += (size_t)NB * BSTRIDE * 4; align16();
    int* rowtot  = (int*)(ws + o); o += 512 * 4; align16();
    int* base    = (int*)(ws + o); o += 513 * 4; align16();
    int* done    = (int*)(ws + o); o += 16; align16();
    int* off     = (int*)(ws + o); o += ((size_t)N + 1) * 4; align16();
    float* dinv  = (float*)(ws + o); o += (size_t)N * 4; align16();
    int* packed  = (int*)(ws + o); o += (size_t)E * 4; align16();
    int* ssrc    = (int*)(ws + o); o += (size_t)E * 4; align16();
    __half* hsh  = (__half*)(ws + o); o += (size_t)N * 64 * 2; align16();
    __half* gsh  = (__half*)(ws + o); o += (size_t)N * 32 * 2; align16();
    float* outp  = (float*)d_out;

    blkhist_kernel<<<NB, 256, 0, stream>>>(dst, E, blkcnt, done, B);
    rowscan_kernel<<<B, 256, 0, stream>>>(blkcnt, rowtot, base, off, done, B,
                                          E, N);
    scatter2_kernel<<<NB, 256, 0, stream>>>(src, dst, blkcnt, base, packed, E,
                                            B);
    bsort_kernel<<<B, 256, 0, stream>>>(packed, base, ssrc, off, dinv, N);
    gemm1_kernel<<<(N + 511) / 512, 256, 0, stream>>>(x, W1, dinv, hsh, N);
    agg1g2_kernel<<<(N + 15) / 16, 256, 0, stream>>>(
        (const uint2*)hsh, ssrc, off, dinv, b1, W2, gsh, N);
    int g2 = (int)(((size_t)((N + 7) / 8) * 64 + 255) / 256);
    agg2_kernel<<<g2, 256, 0, stream>>>((const uint2*)gsh, ssrc, off, dinv, b2,
                                        outp, N);
}